// Round 6
// baseline (1203.826 us; speedup 1.0000x reference)
//
#include <hip/hip_runtime.h>
#include <hip/hip_bf16.h>
#include <stdint.h>

#define NNODES 100000
#define NEDGES 1600000
#define NB 196   // dst buckets of 512 nodes

typedef __attribute__((ext_vector_type(8))) short bf16x8;
typedef __attribute__((ext_vector_type(4))) float f32x4;
typedef __attribute__((ext_vector_type(4))) unsigned short us4;

__device__ __forceinline__ unsigned short f2bf(float f) {
    unsigned int u = __float_as_uint(f);
    unsigned int r = (u + 0x7fffu + ((u >> 16) & 1u)) >> 16;   // RNE
    return (unsigned short)r;
}
__device__ __forceinline__ float bfhi(unsigned int v) { return __uint_as_float(v & 0xffff0000u); }
__device__ __forceinline__ float bflo(unsigned int v) { return __uint_as_float(v << 16); }

// ---------------- CSR build ----------------

__global__ __launch_bounds__(256) void k_zero_i(int* __restrict__ p, int n) {
    int i = blockIdx.x * 256 + threadIdx.x;
    if (i < n) p[i] = 0;
}

__global__ __launch_bounds__(256) void k_bkt_hist(const int* __restrict__ dst,
                                                  int* __restrict__ bkt_cnt, int e) {
    __shared__ int cnt[NB];
    int t = threadIdx.x;
    if (t < NB) cnt[t] = 0;
    __syncthreads();
    int base = blockIdx.x * 4096;
    #pragma unroll
    for (int k = 0; k < 16; ++k) {
        int i = base + k * 256 + t;
        if (i < e) atomicAdd(&cnt[dst[i] >> 9], 1);
    }
    __syncthreads();
    if (t < NB && cnt[t]) atomicAdd(&bkt_cnt[t], cnt[t]);
}

__global__ __launch_bounds__(256) void k_bkt_scan(const int* __restrict__ bkt_cnt,
                                                  int* __restrict__ bkt_base,
                                                  int* __restrict__ bcursor,
                                                  int* __restrict__ row_start, int e, int n) {
    __shared__ int s[256];
    int t = threadIdx.x;
    int v = (t < NB) ? bkt_cnt[t] : 0;
    s[t] = v; __syncthreads();
    for (int off = 1; off < 256; off <<= 1) {
        int u = (t >= off) ? s[t - off] : 0;
        __syncthreads();
        s[t] += u;
        __syncthreads();
    }
    if (t < NB) { int ex = s[t] - v; bkt_base[t] = ex; bcursor[t] = ex; }
    if (t == 0) { bkt_base[NB] = e; row_start[n] = e; }
}

__global__ __launch_bounds__(256) void k_bucketize(const int* __restrict__ src,
                                                   const int* __restrict__ dst,
                                                   int* __restrict__ bcursor,
                                                   int* __restrict__ tmp, int e) {
    __shared__ int cnt[NB];
    __shared__ int gbase[NB];
    int t = threadIdx.x;
    if (t < NB) cnt[t] = 0;
    __syncthreads();
    int base = blockIdx.x * 4096;
    int off[16], pk[16];
    #pragma unroll
    for (int k = 0; k < 16; ++k) {
        int i = base + k * 256 + t;
        off[k] = -1;
        if (i < e) {
            int s = src[i], d = dst[i];
            int b = d >> 9;
            off[k] = atomicAdd(&cnt[b], 1) | (b << 16);
            pk[k] = (s << 9) | (d & 511);
        }
    }
    __syncthreads();
    if (t < NB && cnt[t]) gbase[t] = atomicAdd(&bcursor[t], cnt[t]);
    __syncthreads();
    #pragma unroll
    for (int k = 0; k < 16; ++k) {
        if (off[k] >= 0) {
            int b = off[k] >> 16, o = off[k] & 0xffff;
            tmp[gbase[b] + o] = pk[k];
        }
    }
}

__global__ __launch_bounds__(256) void k_csr(const int* __restrict__ bkt_base,
                                             const int* __restrict__ tmp,
                                             int* __restrict__ perm,
                                             int* __restrict__ row_start,
                                             float* __restrict__ dis, int n) {
    __shared__ int cnt[512], sA[512], sB[512];
    int b = blockIdx.x, t = threadIdx.x;
    int beg = bkt_base[b], end = bkt_base[b + 1];
    int node0 = b << 9;
    int nnode = n - node0; if (nnode > 512) nnode = 512;
    cnt[t] = 0; cnt[t + 256] = 0;
    __syncthreads();
    for (int i = beg + t; i < end; i += 256)
        atomicAdd(&cnt[tmp[i] & 511], 1);
    __syncthreads();
    int* cur = sA; int* nxt = sB;
    cur[t] = cnt[t]; cur[t + 256] = cnt[t + 256];
    __syncthreads();
    for (int off = 1; off < 512; off <<= 1) {
        for (int j = t; j < 512; j += 256)
            nxt[j] = cur[j] + ((j >= off) ? cur[j - off] : 0);
        __syncthreads();
        int* tp = cur; cur = nxt; nxt = tp;
    }
    for (int j = t; j < 512; j += 256) {
        int rs = beg + cur[j] - cnt[j];
        if (j < nnode) {
            row_start[node0 + j] = rs;
            dis[node0 + j] = rsqrtf((float)cnt[j] + 1.0f);
        }
        nxt[j] = rs;
    }
    __syncthreads();
    for (int i = beg + t; i < end; i += 256) {
        int v = tmp[i];
        int p = atomicAdd(&nxt[v & 511], 1);
        perm[p] = v >> 9;
    }
}

// ---------------- MFMA bf16 GEMM -> slice-major g[8][N][16] ----------------
// MODE 0: f32 input (ld 128) + copy x tile into hreg (stride 512)
// MODE 1: bf16 slice-major input hc[8][N][16]

template<int MODE>
__global__ __launch_bounds__(256) void k_gemm_mfma(const void* __restrict__ Xv,
                                                   const float* __restrict__ W,
                                                   const float* __restrict__ dis,
                                                   unsigned short* __restrict__ g,
                                                   float* __restrict__ xcopy,
                                                   int n) {
    __shared__ unsigned short As[128 * 128];   // [row][k] bf16, XOR-swizzled
    __shared__ unsigned short Bs[128 * 128];   // Wt[n][k] bf16, XOR-swizzled
    __shared__ float sdis[128];
    int t = threadIdx.x;
    int base = blockIdx.x * 128;

    // W [k][n] f32 -> Bs transposed bf16
    #pragma unroll
    for (int j = 0; j < 16; ++j) {
        int i4 = t + j * 256;
        int k = i4 >> 5, n4 = (i4 & 31) * 4;
        float4 w = ((const float4*)W)[i4];
        Bs[((n4 + 0) * 128 + k) ^ (((n4 + 0) & 7) << 3)] = f2bf(w.x);
        Bs[((n4 + 1) * 128 + k) ^ (((n4 + 1) & 7) << 3)] = f2bf(w.y);
        Bs[((n4 + 2) * 128 + k) ^ (((n4 + 2) & 7) << 3)] = f2bf(w.z);
        Bs[((n4 + 3) * 128 + k) ^ (((n4 + 3) & 7) << 3)] = f2bf(w.w);
    }
    if (MODE == 0) {
        const float* X = (const float*)Xv;
        #pragma unroll
        for (int j = 0; j < 16; ++j) {
            int i4 = t + j * 256;
            int row = i4 >> 5, c4 = i4 & 31;
            int rg = base + row;
            bool ok = rg < n; if (!ok) rg = n - 1;
            float4 xv = *(const float4*)(X + (size_t)rg * 128 + c4 * 4);
            us4 u; u.x = f2bf(xv.x); u.y = f2bf(xv.y); u.z = f2bf(xv.z); u.w = f2bf(xv.w);
            int idx = (row * 128 + c4 * 4) ^ ((row & 7) << 3);
            *(us4*)&As[idx] = u;
            if (ok) *(float4*)(xcopy + (size_t)rg * 512 + c4 * 4) = xv;
        }
    } else {
        const unsigned short* X = (const unsigned short*)Xv;
        #pragma unroll
        for (int j = 0; j < 8; ++j) {
            int i8 = t + j * 256;                 // 2048 groups of 8
            int row = i8 >> 4, c8 = i8 & 15;
            int rg = base + row; if (rg >= n) rg = n - 1;
            int slice = c8 >> 1, o8 = c8 & 1;
            bf16x8 v = *(const bf16x8*)(X + ((size_t)slice * n + rg) * 16 + o8 * 8);
            int idx = (row * 128 + c8 * 8) ^ ((row & 7) << 3);
            *(bf16x8*)&As[idx] = v;
        }
    }
    if (t < 128) { int rg = base + t; sdis[t] = (rg < n) ? dis[rg] : 0.f; }
    __syncthreads();

    int w = t >> 6, l = t & 63;
    int wm = (w >> 1) * 64, wn = (w & 1) * 64;
    int lr = l & 15, lq = l >> 4;
    f32x4 acc[4][4] = {};
    #pragma unroll
    for (int ks = 0; ks < 4; ++ks) {
        bf16x8 a[4], bb[4];
        #pragma unroll
        for (int mi = 0; mi < 4; ++mi) {
            int row = wm + mi * 16 + lr;
            a[mi] = *(const bf16x8*)&As[(row * 128 + ks * 32 + lq * 8) ^ ((row & 7) << 3)];
        }
        #pragma unroll
        for (int ni = 0; ni < 4; ++ni) {
            int col = wn + ni * 16 + lr;
            bb[ni] = *(const bf16x8*)&Bs[(col * 128 + ks * 32 + lq * 8) ^ ((col & 7) << 3)];
        }
        #pragma unroll
        for (int mi = 0; mi < 4; ++mi)
            #pragma unroll
            for (int ni = 0; ni < 4; ++ni)
                acc[mi][ni] = __builtin_amdgcn_mfma_f32_16x16x32_bf16(a[mi], bb[ni], acc[mi][ni], 0, 0, 0);
    }

    #pragma unroll
    for (int mi = 0; mi < 4; ++mi) {
        #pragma unroll
        for (int r = 0; r < 4; ++r) {
            int rl = wm + mi * 16 + lq * 4 + r;
            int grow = base + rl;
            if (grow < n) {
                float dv = sdis[rl];
                #pragma unroll
                for (int ni = 0; ni < 4; ++ni) {
                    int slice = (wn >> 4) + ni;
                    g[((size_t)slice * n + grow) * 16 + lr] = f2bf(acc[mi][ni][r] * dv);
                }
            }
        }
    }
}

// ---------------- sliced gather: per slice s (16 cols), L2-resident table ----------------
// wave = 1 node (4 nodes sequential); 8 lanes per edge, 8 edges in flight

__global__ __launch_bounds__(256) void k_gather_slice(
        const unsigned short* __restrict__ g,   // [8][N][16]
        const int* __restrict__ row_start,
        const int* __restrict__ perm,
        const float* __restrict__ dis,
        const float* __restrict__ bias,         // [128]
        float* __restrict__ hcol,               // pre-offset, stride 512
        unsigned short* __restrict__ hc,        // [8][N][16] or null
        int n) {
    int s = blockIdx.y;
    int wave = (int)((blockIdx.x * 256u + threadIdx.x) >> 6);
    int lane = threadIdx.x & 63;
    int slot = lane >> 3, p = lane & 7;
    const unsigned short* gs = g + (size_t)s * n * 16;
    float2 bb = *(const float2*)(bias + s * 16 + p * 2);
    int w0 = wave * 4;
    for (int w = w0; w < w0 + 4 && w < n; ++w) {
        int beg = row_start[w], end = row_start[w + 1];
        float ax = 0.f, ay = 0.f;
        for (int e0 = beg; e0 < end; e0 += 8) {
            int e = e0 + slot;
            unsigned int u = 0;
            if (e < end) {
                int si = perm[e];
                u = *(const unsigned int*)(gs + (size_t)si * 16 + p * 2);
            }
            ax += bflo(u); ay += bfhi(u);
        }
        ax += __shfl_xor(ax, 8);  ay += __shfl_xor(ay, 8);
        ax += __shfl_xor(ax, 16); ay += __shfl_xor(ay, 16);
        ax += __shfl_xor(ax, 32); ay += __shfl_xor(ay, 32);
        if (slot == 0) {
            unsigned int u = *(const unsigned int*)(gs + (size_t)w * 16 + p * 2);  // self loop
            ax += bflo(u); ay += bfhi(u);
            float dv = dis[w];
            float2 o = make_float2(ax * dv + bb.x, ay * dv + bb.y);
            *(float2*)(hcol + (size_t)w * 512 + s * 16 + p * 2) = o;
            if (hc) {
                ushort2 hv; hv.x = f2bf(o.x); hv.y = f2bf(o.y);
                *(ushort2*)(hc + ((size_t)s * n + w) * 16 + p * 2) = hv;
            }
        }
    }
}

// ---------------- final linear: pred = h @ W_lin + b_lin ----------------

__global__ __launch_bounds__(256) void k_final(const float* __restrict__ h,
                                               const float* __restrict__ Wl,
                                               const float* __restrict__ bl,
                                               float* __restrict__ out, int n) {
    __shared__ float sWt[16][516];
    __shared__ float sh[16][516];
    int t = threadIdx.x;
    for (int i = t; i < 8192; i += 256) {
        int k = i >> 4, j = i & 15;
        sWt[j][k] = Wl[i];
    }
    int base = blockIdx.x * 16;
    for (int i = t; i < 16 * 128; i += 256) {
        int r = i >> 7, c4 = i & 127;
        float4 v = ((const float4*)(h + (size_t)(base + r) * 512))[c4];
        *(float4*)&sh[r][c4 * 4] = v;
    }
    __syncthreads();
    int node = t >> 4, j = t & 15;
    float acc = bl[j];
    const float4* shp = (const float4*)&sh[node][0];
    const float4* swp = (const float4*)&sWt[j][0];
    #pragma unroll 4
    for (int k4 = 0; k4 < 128; ++k4) {
        float4 a = shp[k4], b = swp[k4];
        acc += a.x * b.x + a.y * b.y + a.z * b.z + a.w * b.w;
    }
    out[(size_t)(base + node) * 16 + j] = acc;
}

// ---------------- launcher ----------------

extern "C" void kernel_launch(void* const* d_in, const int* in_sizes, int n_in,
                              void* d_out, int out_size, void* d_ws, size_t ws_size,
                              hipStream_t stream) {
    const float* x  = (const float*)d_in[0];
    const int* edges = (const int*)d_in[1];
    const int* src = edges;
    const int* dst = edges + NEDGES;
    const float* W1 = (const float*)d_in[2];
    const float* b1 = (const float*)d_in[3];
    const float* W2 = (const float*)d_in[4];
    const float* b2 = (const float*)d_in[5];
    const float* W3 = (const float*)d_in[6];
    const float* b3 = (const float*)d_in[7];
    const float* Wl = (const float*)d_in[8];
    const float* bl = (const float*)d_in[9];

    float* outp = (float*)d_out;
    float* pred = outp;                        // [N,16]
    float* hreg = outp + (size_t)NNODES * 16;  // [N,512]

    unsigned short* g  = (unsigned short*)d_ws;            // [8][N][16] bf16
    unsigned short* hc = g + (size_t)NNODES * 128;         // [8][N][16] bf16
    float* dis   = (float*)(hc + (size_t)NNODES * 128);    // N
    int* tmp     = (int*)(dis + NNODES);                   // E
    int* perm    = tmp + NEDGES;                           // E
    int* row_start = perm + NEDGES;                        // N+1
    int* bkt_cnt  = row_start + NNODES + 1;                // NB
    int* bkt_base = bkt_cnt + NB;                          // NB+1
    int* bcursor  = bkt_base + NB + 1;                     // NB

    int n = NNODES, e = NEDGES;
    int eb = (e + 4095) / 4096;

    k_zero_i<<<1, 256, 0, stream>>>(bkt_cnt, NB);
    k_bkt_hist<<<eb, 256, 0, stream>>>(dst, bkt_cnt, e);
    k_bkt_scan<<<1, 256, 0, stream>>>(bkt_cnt, bkt_base, bcursor, row_start, e, n);
    k_bucketize<<<eb, 256, 0, stream>>>(src, dst, bcursor, tmp, e);
    k_csr<<<NB, 256, 0, stream>>>(bkt_base, tmp, perm, row_start, dis, n);

    const float* Wmats[3] = {W1, W2, W3};
    const float* bvecs[3] = {b1, b2, b3};
    dim3 ggrid(6250, 8);
    for (int L = 0; L < 3; ++L) {
        float* hcol = hreg + 128 * (L + 1);
        unsigned short* hcout = (L < 2) ? hc : nullptr;
        if (L == 0)
            k_gemm_mfma<0><<<(n + 127) / 128, 256, 0, stream>>>(x, Wmats[L], dis, g, hreg, n);
        else
            k_gemm_mfma<1><<<(n + 127) / 128, 256, 0, stream>>>(hc, Wmats[L], dis, g, nullptr, n);
        k_gather_slice<<<ggrid, 256, 0, stream>>>(g, row_start, perm, dis,
                                                  bvecs[L], hcol, hcout, n);
    }
    k_final<<<n / 16, 256, 0, stream>>>(hreg, Wl, bl, pred, n);
}

// Round 7
// 666.369 us; speedup vs baseline: 1.8065x; 1.8065x over previous
//
#include <hip/hip_runtime.h>
#include <hip/hip_bf16.h>
#include <stdint.h>

#define NNODES 100000
#define NEDGES 1600000
#define NB 196   // dst buckets of 512 nodes

typedef __attribute__((ext_vector_type(8))) short bf16x8;
typedef __attribute__((ext_vector_type(4))) float f32x4;
typedef __attribute__((ext_vector_type(4))) unsigned short us4;

__device__ __forceinline__ unsigned short f2bf(float f) {
    unsigned int u = __float_as_uint(f);
    unsigned int r = (u + 0x7fffu + ((u >> 16) & 1u)) >> 16;   // RNE
    return (unsigned short)r;
}
__device__ __forceinline__ float bf2f(unsigned short s) {
    return __uint_as_float(((unsigned int)s) << 16);
}
__device__ __forceinline__ float4 bf4f(us4 u) {
    return make_float4(bf2f(u.x), bf2f(u.y), bf2f(u.z), bf2f(u.w));
}

// ---------------- CSR build ----------------

__global__ __launch_bounds__(256) void k_zero_i(int* __restrict__ p, int n) {
    int i = blockIdx.x * 256 + threadIdx.x;
    if (i < n) p[i] = 0;
}

__global__ __launch_bounds__(256) void k_bkt_hist(const int* __restrict__ dst,
                                                  int* __restrict__ bkt_cnt, int e) {
    __shared__ int cnt[NB];
    int t = threadIdx.x;
    if (t < NB) cnt[t] = 0;
    __syncthreads();
    int base = blockIdx.x * 4096;
    #pragma unroll
    for (int k = 0; k < 16; ++k) {
        int i = base + k * 256 + t;
        if (i < e) atomicAdd(&cnt[dst[i] >> 9], 1);
    }
    __syncthreads();
    if (t < NB && cnt[t]) atomicAdd(&bkt_cnt[t], cnt[t]);
}

__global__ __launch_bounds__(256) void k_bkt_scan(const int* __restrict__ bkt_cnt,
                                                  int* __restrict__ bkt_base,
                                                  int* __restrict__ bcursor,
                                                  int* __restrict__ row_start, int e, int n) {
    __shared__ int s[256];
    int t = threadIdx.x;
    int v = (t < NB) ? bkt_cnt[t] : 0;
    s[t] = v; __syncthreads();
    for (int off = 1; off < 256; off <<= 1) {
        int u = (t >= off) ? s[t - off] : 0;
        __syncthreads();
        s[t] += u;
        __syncthreads();
    }
    if (t < NB) { int ex = s[t] - v; bkt_base[t] = ex; bcursor[t] = ex; }
    if (t == 0) { bkt_base[NB] = e; row_start[n] = e; }
}

__global__ __launch_bounds__(256) void k_bucketize(const int* __restrict__ src,
                                                   const int* __restrict__ dst,
                                                   int* __restrict__ bcursor,
                                                   int* __restrict__ tmp, int e) {
    __shared__ int cnt[NB];
    __shared__ int gbase[NB];
    int t = threadIdx.x;
    if (t < NB) cnt[t] = 0;
    __syncthreads();
    int base = blockIdx.x * 4096;
    int off[16], pk[16];
    #pragma unroll
    for (int k = 0; k < 16; ++k) {
        int i = base + k * 256 + t;
        off[k] = -1;
        if (i < e) {
            int s = src[i], d = dst[i];
            int b = d >> 9;
            off[k] = atomicAdd(&cnt[b], 1) | (b << 16);
            pk[k] = (s << 9) | (d & 511);
        }
    }
    __syncthreads();
    if (t < NB && cnt[t]) gbase[t] = atomicAdd(&bcursor[t], cnt[t]);
    __syncthreads();
    #pragma unroll
    for (int k = 0; k < 16; ++k) {
        if (off[k] >= 0) {
            int b = off[k] >> 16, o = off[k] & 0xffff;
            tmp[gbase[b] + o] = pk[k];
        }
    }
}

__global__ __launch_bounds__(256) void k_csr(const int* __restrict__ bkt_base,
                                             const int* __restrict__ tmp,
                                             int* __restrict__ perm,
                                             int* __restrict__ row_start,
                                             float* __restrict__ dis, int n) {
    __shared__ int cnt[512], sA[512], sB[512];
    int b = blockIdx.x, t = threadIdx.x;
    int beg = bkt_base[b], end = bkt_base[b + 1];
    int node0 = b << 9;
    int nnode = n - node0; if (nnode > 512) nnode = 512;
    cnt[t] = 0; cnt[t + 256] = 0;
    __syncthreads();
    for (int i = beg + t; i < end; i += 256)
        atomicAdd(&cnt[tmp[i] & 511], 1);
    __syncthreads();
    int* cur = sA; int* nxt = sB;
    cur[t] = cnt[t]; cur[t + 256] = cnt[t + 256];
    __syncthreads();
    for (int off = 1; off < 512; off <<= 1) {
        for (int j = t; j < 512; j += 256)
            nxt[j] = cur[j] + ((j >= off) ? cur[j - off] : 0);
        __syncthreads();
        int* tp = cur; cur = nxt; nxt = tp;
    }
    for (int j = t; j < 512; j += 256) {
        int rs = beg + cur[j] - cnt[j];
        if (j < nnode) {
            row_start[node0 + j] = rs;
            dis[node0 + j] = rsqrtf((float)cnt[j] + 1.0f);
        }
        nxt[j] = rs;
    }
    __syncthreads();
    for (int i = beg + t; i < end; i += 256) {
        int v = tmp[i];
        int p = atomicAdd(&nxt[v & 511], 1);
        perm[p] = v >> 9;
    }
}

// ---------------- MFMA bf16 GEMM: g[r] = bf16( (X[r]@W) * dis[r] ), row-major [N][128] --------
// MODE 0: f32 input [N][128]; also writes hreg f32 copy + hc seg0 bf16
// MODE 1: bf16 row-major input [N][128]

template<int MODE>
__global__ __launch_bounds__(256) void k_gemm_mfma(const void* __restrict__ Xv,
                                                   const float* __restrict__ W,
                                                   const float* __restrict__ dis,
                                                   unsigned short* __restrict__ g,
                                                   float* __restrict__ xcopy,
                                                   unsigned short* __restrict__ xc,
                                                   int n) {
    __shared__ unsigned short As[128 * 128];   // [row][k] bf16, XOR-swizzled
    __shared__ unsigned short Bs[128 * 128];   // Wt[n][k] bf16, XOR-swizzled
    __shared__ float sdis[128];
    int t = threadIdx.x;
    int base = blockIdx.x * 128;

    // W [k][n] f32 -> Bs transposed bf16
    #pragma unroll
    for (int j = 0; j < 16; ++j) {
        int i4 = t + j * 256;
        int k = i4 >> 5, n4 = (i4 & 31) * 4;
        float4 w = ((const float4*)W)[i4];
        Bs[((n4 + 0) * 128 + k) ^ (((n4 + 0) & 7) << 3)] = f2bf(w.x);
        Bs[((n4 + 1) * 128 + k) ^ (((n4 + 1) & 7) << 3)] = f2bf(w.y);
        Bs[((n4 + 2) * 128 + k) ^ (((n4 + 2) & 7) << 3)] = f2bf(w.z);
        Bs[((n4 + 3) * 128 + k) ^ (((n4 + 3) & 7) << 3)] = f2bf(w.w);
    }
    if (MODE == 0) {
        const float* X = (const float*)Xv;
        #pragma unroll
        for (int j = 0; j < 16; ++j) {
            int i4 = t + j * 256;
            int row = i4 >> 5, c4 = i4 & 31;
            int rg = base + row;
            bool ok = rg < n; if (!ok) rg = n - 1;
            float4 xv = *(const float4*)(X + (size_t)rg * 128 + c4 * 4);
            us4 u; u.x = f2bf(xv.x); u.y = f2bf(xv.y); u.z = f2bf(xv.z); u.w = f2bf(xv.w);
            int idx = (row * 128 + c4 * 4) ^ ((row & 7) << 3);
            *(us4*)&As[idx] = u;
            if (ok) {
                *(float4*)(xcopy + (size_t)rg * 512 + c4 * 4) = xv;   // h cols 0..127 f32
                *(us4*)(xc + (size_t)rg * 128 + c4 * 4) = u;          // hc seg0 bf16
            }
        }
    } else {
        const unsigned short* X = (const unsigned short*)Xv;
        #pragma unroll
        for (int j = 0; j < 8; ++j) {
            int i8 = t + j * 256;                 // 2048 x bf16x8
            int row = i8 >> 4, c8 = i8 & 15;
            int rg = base + row; if (rg >= n) rg = n - 1;
            bf16x8 v = *(const bf16x8*)(X + (size_t)rg * 128 + c8 * 8);
            int idx = (row * 128 + c8 * 8) ^ ((row & 7) << 3);
            *(bf16x8*)&As[idx] = v;
        }
    }
    if (t < 128) { int rg = base + t; sdis[t] = (rg < n) ? dis[rg] : 0.f; }
    __syncthreads();

    int w = t >> 6, l = t & 63;
    int wm = (w >> 1) * 64, wn = (w & 1) * 64;
    int lr = l & 15, lq = l >> 4;
    f32x4 acc[4][4] = {};
    #pragma unroll
    for (int ks = 0; ks < 4; ++ks) {
        bf16x8 a[4], bb[4];
        #pragma unroll
        for (int mi = 0; mi < 4; ++mi) {
            int row = wm + mi * 16 + lr;
            a[mi] = *(const bf16x8*)&As[(row * 128 + ks * 32 + lq * 8) ^ ((row & 7) << 3)];
        }
        #pragma unroll
        for (int ni = 0; ni < 4; ++ni) {
            int col = wn + ni * 16 + lr;
            bb[ni] = *(const bf16x8*)&Bs[(col * 128 + ks * 32 + lq * 8) ^ ((col & 7) << 3)];
        }
        #pragma unroll
        for (int mi = 0; mi < 4; ++mi)
            #pragma unroll
            for (int ni = 0; ni < 4; ++ni)
                acc[mi][ni] = __builtin_amdgcn_mfma_f32_16x16x32_bf16(a[mi], bb[ni], acc[mi][ni], 0, 0, 0);
    }

    #pragma unroll
    for (int mi = 0; mi < 4; ++mi) {
        #pragma unroll
        for (int r = 0; r < 4; ++r) {
            int rl = wm + mi * 16 + lq * 4 + r;
            int grow = base + rl;
            if (grow < n) {
                float dv = sdis[rl];
                #pragma unroll
                for (int ni = 0; ni < 4; ++ni)
                    g[(size_t)grow * 128 + wn + ni * 16 + lr] = f2bf(acc[mi][ni][r] * dv);
            }
        }
    }
}

// ---------------- gather: hcol[v] = (g[v] + sum g[u]) * dis[v] + bias ----------------
// 2 nodes per wave (32 lanes each, ushort4 = 4 cols/lane), 8 rows in flight per node

__global__ __launch_bounds__(256) void k_gather2(
        const unsigned short* __restrict__ g,   // [N][128] bf16
        const int* __restrict__ row_start,
        const int* __restrict__ perm,
        const float* __restrict__ dis,
        const float* __restrict__ bias,         // [128]
        float* __restrict__ hcol,               // pre-offset, stride 512
        unsigned short* __restrict__ hc,        // [N][128] bf16 segment
        int n) {
    int tid = blockIdx.x * 256 + threadIdx.x;
    int lane = threadIdx.x & 63;
    int half = lane >> 5, li = lane & 31;
    int w = (tid >> 6) * 2 + half;
    if (w >= n) return;

    float4 bb = *(const float4*)(bias + li * 4);
    int beg = row_start[w], end = row_start[w + 1];

    float4 a = bf4f(*(const us4*)(g + (size_t)w * 128 + li * 4));   // self loop

    int ei = beg;
    for (; ei + 7 < end; ei += 8) {
        int s0 = perm[ei + 0], s1 = perm[ei + 1], s2 = perm[ei + 2], s3 = perm[ei + 3];
        int s4 = perm[ei + 4], s5 = perm[ei + 5], s6 = perm[ei + 6], s7 = perm[ei + 7];
        us4 v0 = *(const us4*)(g + (size_t)s0 * 128 + li * 4);
        us4 v1 = *(const us4*)(g + (size_t)s1 * 128 + li * 4);
        us4 v2 = *(const us4*)(g + (size_t)s2 * 128 + li * 4);
        us4 v3 = *(const us4*)(g + (size_t)s3 * 128 + li * 4);
        us4 v4 = *(const us4*)(g + (size_t)s4 * 128 + li * 4);
        us4 v5 = *(const us4*)(g + (size_t)s5 * 128 + li * 4);
        us4 v6 = *(const us4*)(g + (size_t)s6 * 128 + li * 4);
        us4 v7 = *(const us4*)(g + (size_t)s7 * 128 + li * 4);
        float4 f0 = bf4f(v0), f1 = bf4f(v1), f2 = bf4f(v2), f3 = bf4f(v3);
        float4 f4 = bf4f(v4), f5 = bf4f(v5), f6 = bf4f(v6), f7 = bf4f(v7);
        a.x += ((f0.x + f1.x) + (f2.x + f3.x)) + ((f4.x + f5.x) + (f6.x + f7.x));
        a.y += ((f0.y + f1.y) + (f2.y + f3.y)) + ((f4.y + f5.y) + (f6.y + f7.y));
        a.z += ((f0.z + f1.z) + (f2.z + f3.z)) + ((f4.z + f5.z) + (f6.z + f7.z));
        a.w += ((f0.w + f1.w) + (f2.w + f3.w)) + ((f4.w + f5.w) + (f6.w + f7.w));
    }
    for (; ei < end; ++ei) {
        float4 f = bf4f(*(const us4*)(g + (size_t)perm[ei] * 128 + li * 4));
        a.x += f.x; a.y += f.y; a.z += f.z; a.w += f.w;
    }

    float dv = dis[w];
    float4 o = make_float4(a.x * dv + bb.x, a.y * dv + bb.y,
                           a.z * dv + bb.z, a.w * dv + bb.w);
    *(float4*)(hcol + (size_t)w * 512 + li * 4) = o;
    us4 hv; hv.x = f2bf(o.x); hv.y = f2bf(o.y); hv.z = f2bf(o.z); hv.w = f2bf(o.w);
    *(us4*)(hc + (size_t)w * 128 + li * 4) = hv;
}

// ---------------- final linear from bf16 concat: pred = hcat @ W_lin + b_lin ----------------
// hcat = [4][N][128] bf16 (x, c1, c2, c3)

__global__ __launch_bounds__(256) void k_final_bf(const unsigned short* __restrict__ hcat,
                                                  const float* __restrict__ Wl,  // [512][16]
                                                  const float* __restrict__ bl,
                                                  float* __restrict__ out, int n) {
    __shared__ float sWt[16][516];          // transposed W_lin
    __shared__ unsigned short sh[16][520];  // 16 nodes x 512 bf16
    int t = threadIdx.x;
    for (int i = t; i < 8192; i += 256) {
        int k = i >> 4, j = i & 15;
        sWt[j][k] = Wl[i];
    }
    int base = blockIdx.x * 16;
    #pragma unroll
    for (int j = 0; j < 8; ++j) {
        int i = t + j * 256;                 // 2048 us4 loads
        int r = i >> 7, q = i & 127;
        int seg = q >> 5, c4 = q & 31;
        us4 v = *(const us4*)(hcat + ((size_t)seg * n + base + r) * 128 + c4 * 4);
        *(us4*)&sh[r][seg * 128 + c4 * 4] = v;
    }
    __syncthreads();
    int node = t >> 4, j = t & 15;
    float acc = bl[j];
    #pragma unroll 4
    for (int k4 = 0; k4 < 128; ++k4) {
        float4 h = bf4f(*(const us4*)&sh[node][k4 * 4]);
        float4 wv = *(const float4*)&sWt[j][k4 * 4];
        acc += h.x * wv.x + h.y * wv.y + h.z * wv.z + h.w * wv.w;
    }
    out[(size_t)(base + node) * 16 + j] = acc;
}

// ---------------- launcher ----------------

extern "C" void kernel_launch(void* const* d_in, const int* in_sizes, int n_in,
                              void* d_out, int out_size, void* d_ws, size_t ws_size,
                              hipStream_t stream) {
    const float* x  = (const float*)d_in[0];
    const int* edges = (const int*)d_in[1];
    const int* src = edges;
    const int* dst = edges + NEDGES;
    const float* W1 = (const float*)d_in[2];
    const float* b1 = (const float*)d_in[3];
    const float* W2 = (const float*)d_in[4];
    const float* b2 = (const float*)d_in[5];
    const float* W3 = (const float*)d_in[6];
    const float* b3 = (const float*)d_in[7];
    const float* Wl = (const float*)d_in[8];
    const float* bl = (const float*)d_in[9];

    float* outp = (float*)d_out;
    float* pred = outp;                        // [N,16]
    float* hreg = outp + (size_t)NNODES * 16;  // [N,512]

    unsigned short* g  = (unsigned short*)d_ws;            // [N][128] bf16
    unsigned short* hc = g + (size_t)NNODES * 128;         // [4][N][128] bf16
    float* dis   = (float*)(hc + (size_t)NNODES * 512);    // N
    int* tmp     = (int*)(dis + NNODES);                   // E
    int* perm    = tmp + NEDGES;                           // E
    int* row_start = perm + NEDGES;                        // N+1
    int* bkt_cnt  = row_start + NNODES + 1;                // NB
    int* bkt_base = bkt_cnt + NB;                          // NB+1
    int* bcursor  = bkt_base + NB + 1;                     // NB

    int n = NNODES, e = NEDGES;
    int eb = (e + 4095) / 4096;

    k_zero_i<<<1, 256, 0, stream>>>(bkt_cnt, NB);
    k_bkt_hist<<<eb, 256, 0, stream>>>(dst, bkt_cnt, e);
    k_bkt_scan<<<1, 256, 0, stream>>>(bkt_cnt, bkt_base, bcursor, row_start, e, n);
    k_bucketize<<<eb, 256, 0, stream>>>(src, dst, bcursor, tmp, e);
    k_csr<<<NB, 256, 0, stream>>>(bkt_base, tmp, perm, row_start, dis, n);

    const float* Wmats[3] = {W1, W2, W3};
    const float* bvecs[3] = {b1, b2, b3};
    int gb = (n + 7) / 8;   // gather: 8 nodes per block (4 waves x 2)
    for (int L = 0; L < 3; ++L) {
        float* hcol = hreg + 128 * (L + 1);
        unsigned short* hcseg = hc + (size_t)(L + 1) * NNODES * 128;
        if (L == 0)
            k_gemm_mfma<0><<<(n + 127) / 128, 256, 0, stream>>>(x, Wmats[L], dis, g,
                                                                hreg, hc, n);
        else
            k_gemm_mfma<1><<<(n + 127) / 128, 256, 0, stream>>>(hc + (size_t)L * NNODES * 128,
                                                                Wmats[L], dis, g,
                                                                nullptr, nullptr, n);
        k_gather2<<<gb, 256, 0, stream>>>(g, row_start, perm, dis, bvecs[L], hcol, hcseg, n);
    }
    k_final_bf<<<n / 16, 256, 0, stream>>>(hc, Wl, bl, pred, n);
}